// Round 4
// baseline (397.039 us; speedup 1.0000x reference)
//
#include <hip/hip_runtime.h>
#include <hip/hip_bf16.h>
#include <math.h>

// Problem constants (fixed by setup_inputs)
#define DM 1024          // d_model
#define NS 16            // d_state
#define BSZ 8
#define LSEQ 1024
#define MROWS (BSZ*LSEQ) // 8192 token rows
#define CH 32            // scan chunk (timesteps staged per LDS buffer)

typedef __bf16 bf16;
typedef bf16 bf16x8 __attribute__((ext_vector_type(8)));
typedef bf16 bf16x4 __attribute__((ext_vector_type(4)));
typedef float f32x4 __attribute__((ext_vector_type(4)));
typedef unsigned int u32;
typedef unsigned short u16;

__device__ __forceinline__ void async16(const void* g, void* l) {
  __builtin_amdgcn_global_load_lds((const __attribute__((address_space(1))) void*)g,
                                   (__attribute__((address_space(3))) void*)l,
                                   16, 0, 0);
}

// packed (dt, xi) word: dt bf16 in low 16, xi bf16 in high 16
__device__ __forceinline__ float bflo(u32 u) { return __builtin_bit_cast(float, (u32)(u << 16)); }
__device__ __forceinline__ float bfhi(u32 u) { return __builtin_bit_cast(float, (u32)(u & 0xffff0000u)); }

// DPP row_ror add chain: 16-lane row reduction on the VALU pipe (no LDS traffic)
template <int CTRL>
__device__ __forceinline__ float dpp_add(float v) {
  int x = __builtin_amdgcn_update_dpp(0, __builtin_bit_cast(int, v), CTRL, 0xf, 0xf, true);
  return v + __builtin_bit_cast(float, x);
}
__device__ __forceinline__ float row_reduce16(float p) {
  p = dpp_add<0x121>(p);
  p = dpp_add<0x122>(p);
  p = dpp_add<0x124>(p);
  p = dpp_add<0x128>(p);
  return p;
}

// ---------------------------------------------------------------------------
// f32 -> bf16 cast (weights)
// ---------------------------------------------------------------------------
__global__ void cast_f2b(const float* __restrict__ s, bf16* __restrict__ d, int n4) {
  int i = blockIdx.x * 256 + threadIdx.x;
  if (i < n4) {
    float4 v = ((const float4*)s)[i];
    bf16x4 o;
    o.x = (bf16)v.x; o.y = (bf16)v.y; o.z = (bf16)v.z; o.w = (bf16)v.w;
    *(bf16x4*)(d + 4 * (size_t)i) = o;
  }
}

// ---------------------------------------------------------------------------
// Transpose + cast: dst[k][d] = (bf16) src[d][k], 1024x1024. 64x64 LDS tiles.
// ---------------------------------------------------------------------------
__global__ void transpose_cast(const float* __restrict__ src, bf16* __restrict__ dst) {
  __shared__ float tile[64][65];
  const int bk = blockIdx.x * 64;
  const int bd = blockIdx.y * 64;
  const int t = threadIdx.x;
  const int c4 = t & 15;
  const int r0 = t >> 4;
#pragma unroll
  for (int p = 0; p < 4; ++p) {
    int r = r0 + p * 16;
    float4 v = *(const float4*)(src + (size_t)(bd + r) * 1024 + bk + c4 * 4);
    tile[r][c4 * 4 + 0] = v.x;
    tile[r][c4 * 4 + 1] = v.y;
    tile[r][c4 * 4 + 2] = v.z;
    tile[r][c4 * 4 + 3] = v.w;
  }
  __syncthreads();
#pragma unroll
  for (int p = 0; p < 4; ++p) {
    int r = r0 + p * 16;
    bf16x4 o;
    o.x = (bf16)tile[c4 * 4 + 0][r];
    o.y = (bf16)tile[c4 * 4 + 1][r];
    o.z = (bf16)tile[c4 * 4 + 2][r];
    o.w = (bf16)tile[c4 * 4 + 3][r];
    *(bf16x4*)(dst + (size_t)(bk + r) * 1024 + bd + c4 * 4) = o;
  }
}

// ---------------------------------------------------------------------------
// LayerNorm over d=1024, writes bf16 x_norm. One block (256 thr) per row.
// ---------------------------------------------------------------------------
__global__ void ln_kernel(const float* __restrict__ x, const float* __restrict__ g,
                          const float* __restrict__ b, bf16* __restrict__ out) {
  const size_t row = blockIdx.x;
  const int t = threadIdx.x;
  float4 v = ((const float4*)(x + row * DM))[t];
  float s = v.x + v.y + v.z + v.w;
  float s2 = v.x*v.x + v.y*v.y + v.z*v.z + v.w*v.w;
#pragma unroll
  for (int m = 1; m < 64; m <<= 1) { s += __shfl_xor(s, m, 64); s2 += __shfl_xor(s2, m, 64); }
  __shared__ float red[8];
  int wave = t >> 6, lane = t & 63;
  if (lane == 0) { red[wave] = s; red[4 + wave] = s2; }
  __syncthreads();
  s  = red[0] + red[1] + red[2] + red[3];
  s2 = red[4] + red[5] + red[6] + red[7];
  float mu  = s * (1.f / DM);
  float var = s2 * (1.f / DM) - mu * mu;
  float inv = rsqrtf(var + 1e-5f);
  float4 gg = ((const float4*)g)[t];
  float4 bb = ((const float4*)b)[t];
  bf16x4 o;
  o.x = (bf16)((v.x - mu) * inv * gg.x + bb.x);
  o.y = (bf16)((v.y - mu) * inv * gg.y + bb.y);
  o.z = (bf16)((v.z - mu) * inv * gg.z + bb.z);
  o.w = (bf16)((v.w - mu) * inv * gg.w + bb.w);
  *(bf16x4*)(out + row * DM + t * 4) = o;
}

// ---------------------------------------------------------------------------
// MFMA bf16 GEMM: C[M,N] = A[M,K] @ W[N,K]^T. 128x128 tile, BK=64 (two 32-wide
// sub-stages per barrier pair). SWZ: 1D grid, XCD-aware mapping — blk%8 picks
// an 8-m-tile stripe per XCD (A-stripe 2MB stays L2-resident), n-major within.
// EPI 0 (mega): n<1024 -> xi (hi half of dx word); <2048 -> z bf16;
//               <3072 -> softplus dt (lo half of dx); <3088 B_t; <3104 C_t.
// EPI 2: out = acc + residual[m*DM+n]
// EPI 3 (compose): out_b[m*1024+n] = bf16(acc)
// ---------------------------------------------------------------------------
template <int EPI, bool SWZ>
__global__ __launch_bounds__(256)
void gemm_bf16(const bf16* __restrict__ A, const bf16* __restrict__ W, int K,
               float* __restrict__ out_f, bf16* __restrict__ out_b,
               u16* __restrict__ out_dx, const float* __restrict__ aux,
               float* __restrict__ out_f3, float* __restrict__ out_f4) {
  __shared__ bf16 As[2][128 * 32];
  __shared__ bf16 Bs[2][128 * 32];
  int tx, ty;
  if (SWZ) {
    int g = blockIdx.x;           // total = 8 XCD * 8 mloc * ntx
    int xcd = g & 7, slot = g >> 3;
    tx = slot >> 3;               // n-tile (n-major sweep within XCD)
    ty = xcd * 8 + (slot & 7);    // m-tile within this XCD's stripe
  } else {
    tx = blockIdx.x; ty = blockIdx.y;
  }
  const int tid  = threadIdx.x;
  const int wave = tid >> 6, lane = tid & 63;
  const int lr = lane & 15, quad = lane >> 4;
  const size_t arow = (size_t)ty * 128;
  const size_t brow = (size_t)tx * 128;
  f32x4 acc[4][4] = {};

  const int srow = wave * 32 + (lane >> 2);
  const int skc  = (lane & 3) * 8;
  const bf16* ag = A + (arow + srow) * (size_t)K + skc;
  const bf16* wg = W + (brow + srow) * (size_t)K + skc;
  bf16* asl0 = &As[0][wave * 32 * 32];
  bf16* asl1 = &As[1][wave * 32 * 32];
  bf16* bsl0 = &Bs[0][wave * 32 * 32];
  bf16* bsl1 = &Bs[1][wave * 32 * 32];

  for (int k0 = 0; k0 < K; k0 += 64) {
    async16(ag + k0,                       asl0);
    async16(ag + (size_t)16 * K + k0,      asl0 + 16 * 32);
    async16(ag + k0 + 32,                  asl1);
    async16(ag + (size_t)16 * K + k0 + 32, asl1 + 16 * 32);
    async16(wg + k0,                       bsl0);
    async16(wg + (size_t)16 * K + k0,      bsl0 + 16 * 32);
    async16(wg + k0 + 32,                  bsl1);
    async16(wg + (size_t)16 * K + k0 + 32, bsl1 + 16 * 32);
    __syncthreads();
#pragma unroll
    for (int kh = 0; kh < 2; ++kh) {
      const bf16* ap = &As[kh][(((wave >> 1) * 64) + lr) * 32 + quad * 8];
      const bf16* bp = &Bs[kh][(((wave & 1) * 64) + lr) * 32 + quad * 8];
      bf16x8 af[4], bfr[4];
#pragma unroll
      for (int i = 0; i < 4; ++i) af[i] = *(const bf16x8*)(ap + i * 16 * 32);
#pragma unroll
      for (int j = 0; j < 4; ++j) bfr[j] = *(const bf16x8*)(bp + j * 16 * 32);
#pragma unroll
      for (int i = 0; i < 4; ++i)
#pragma unroll
        for (int j = 0; j < 4; ++j)
          acc[i][j] = __builtin_amdgcn_mfma_f32_16x16x32_bf16(af[i], bfr[j], acc[i][j], 0, 0, 0);
    }
    __syncthreads();
  }

  // Epilogue. D layout (verified m89/m91): col = lane&15, row = quad*4 + reg.
  const size_t mbase = arow + (wave >> 1) * 64;
  const size_t nbase = brow + (wave & 1) * 64;
#pragma unroll
  for (int i = 0; i < 4; ++i)
#pragma unroll
    for (int j = 0; j < 4; ++j)
#pragma unroll
      for (int r = 0; r < 4; ++r) {
        size_t m = mbase + i * 16 + quad * 4 + r;
        size_t n = nbase + j * 16 + lr;
        float v = acc[i][j][r];
        if (EPI == 0) {
          if (n < DM) {
            out_dx[2 * (m * DM + n) + 1] = __builtin_bit_cast(u16, (bf16)v);   // xi
          } else if (n < 2 * DM) {
            out_b[m * DM + (n - DM)] = (bf16)v;                                // z
          } else if (n < 3 * DM) {
            float tt = v + aux[n - 2 * DM];
            float sp = (tt > 20.f) ? tt : __logf(1.f + __expf(tt));
            out_dx[2 * (m * DM + (n - 2 * DM))] = __builtin_bit_cast(u16, (bf16)sp);  // dt
          } else if (n < 3 * DM + NS) {
            out_f3[m * NS + (n - 3 * DM)] = v;                                 // B_t
          } else if (n < 3 * DM + 2 * NS) {
            out_f4[m * NS + (n - 3 * DM - NS)] = v;                            // C_t
          } // else: garbage pad columns, discard
        } else if (EPI == 2) {
          out_f[m * DM + n] = v + aux[m * DM + n];
        } else if (EPI == 3) {
          out_b[m * (size_t)DM + n] = (bf16)v;
        }
      }
}

// ---------------------------------------------------------------------------
// Selective scan + fused output gate. Block = (batch b, 16 d-channels);
// thread (dl,n) owns h[b, d0+dl, n]. Packed bf16x2 (dt,xi) words, DPP
// reduction, double-buffered chunks; writes ssm_out = y*silu(z)+xi*D as bf16.
// ---------------------------------------------------------------------------
__global__ __launch_bounds__(256)
void scan_kernel(const u32* __restrict__ dx, const bf16* __restrict__ z_b,
                 const float* __restrict__ B_t, const float* __restrict__ C_t,
                 const float* __restrict__ A_log, const float* __restrict__ h_prev,
                 const float* __restrict__ Dvec,
                 bf16* __restrict__ ssm_out, float* __restrict__ h_final) {
  const int blk = blockIdx.x;        // 512 blocks
  const int b = blk >> 6;
  const int d0 = (blk & 63) * 16;
  const int t = threadIdx.x;
  const int n = t & 15, dl = t >> 4;
  const int d = d0 + dl;
  const float Ac2 = -__expf(A_log[d * NS + n]) * 1.44269504f;  // fold log2e
  float h = h_prev[(size_t)b * DM * NS + (size_t)d * NS + n];

  __shared__ u32    dxs[2][CH][16];  // packed (dt, xi) per (l, dl)
  __shared__ float2 bcs[2][CH][16];  // (B, C) per (l, n)
  __shared__ float  ys[CH][16];

  const size_t base_row = (size_t)b * LSEQ;
  const int l_a = t >> 4,  c_a = t & 15;
  const int l_b = l_a + 16, c_b = c_a;
  const float Dva = Dvec[d0 + c_a];

  float za, zb;
  {
    size_t ga = (base_row + l_a) * DM + d0 + c_a;
    size_t gb = (base_row + l_b) * DM + d0 + c_b;
    dxs[0][l_a][c_a] = dx[ga];
    dxs[0][l_b][c_b] = dx[gb];
    za = (float)z_b[ga]; zb = (float)z_b[gb];
    size_t gB = base_row * NS;
    bcs[0][l_a][c_a] = make_float2(B_t[gB + t],       C_t[gB + t]);
    bcs[0][l_b][c_b] = make_float2(B_t[gB + t + 256], C_t[gB + t + 256]);
  }
  __syncthreads();

  for (int c = 0; c < LSEQ / CH; ++c) {
    const int cur = c & 1, nxt = cur ^ 1;
    u32 pdxa, pdxb; float2 pbca, pbcb; float pza, pzb;
    if (c + 1 < LSEQ / CH) {
      size_t l0 = (size_t)(c + 1) * CH;
      size_t ga = (base_row + l0 + l_a) * DM + d0 + c_a;
      size_t gb = (base_row + l0 + l_b) * DM + d0 + c_b;
      pdxa = dx[ga];
      pdxb = dx[gb];
      pza = (float)z_b[ga]; pzb = (float)z_b[gb];
      size_t gB = (base_row + l0) * NS;
      pbca = make_float2(B_t[gB + t],       C_t[gB + t]);
      pbcb = make_float2(B_t[gB + t + 256], C_t[gB + t + 256]);
    }
#pragma unroll
    for (int l = 0; l < CH; ++l) {
      u32 u = dxs[cur][l][dl];
      float dtv = bflo(u), xiv = bfhi(u);
      float2 bc = bcs[cur][l][n];
      float a = __builtin_amdgcn_exp2f(dtv * Ac2);
      h = fmaf(a, h, (dtv * xiv) * bc.x);
      float p = row_reduce16(h * bc.y);
      if (n == 0) ys[l][dl] = p;
    }
    __syncthreads();
    {
      size_t l0 = (size_t)c * CH;
      float xa = bfhi(dxs[cur][l_a][c_a]);
      float xb = bfhi(dxs[cur][l_b][c_b]);
      float sa = za / (1.f + __expf(-za));
      float sb = zb / (1.f + __expf(-zb));
      ssm_out[(base_row + l0 + l_a) * DM + d0 + c_a] = (bf16)(ys[l_a][c_a] * sa + xa * Dva);
      ssm_out[(base_row + l0 + l_b) * DM + d0 + c_b] = (bf16)(ys[l_b][c_b] * sb + xb * Dva);
    }
    if (c + 1 < LSEQ / CH) {
      dxs[nxt][l_a][c_a] = pdxa;
      dxs[nxt][l_b][c_b] = pdxb;
      bcs[nxt][l_a][c_a] = pbca;
      bcs[nxt][l_b][c_b] = pbcb;
      za = pza; zb = pzb;
    }
    __syncthreads();
  }
  h_final[(size_t)b * DM * NS + (size_t)d0 * NS + t] = h;
}

// ---------------------------------------------------------------------------
extern "C" void kernel_launch(void* const* d_in, const int* in_sizes, int n_in,
                              void* d_out, int out_size, void* d_ws, size_t ws_size,
                              hipStream_t stream) {
  const float* x      = (const float*)d_in[0];
  const float* h_prev = (const float*)d_in[1];
  const float* ln_g   = (const float*)d_in[2];
  const float* ln_b   = (const float*)d_in[3];
  const float* W_ig   = (const float*)d_in[4];
  const float* W_dt   = (const float*)d_in[5];
  const float* b_dt   = (const float*)d_in[6];
  const float* A_log  = (const float*)d_in[7];
  const float* W_B    = (const float*)d_in[8];
  const float* W_C    = (const float*)d_in[9];
  const float* Dvec   = (const float*)d_in[10];
  const float* W_out  = (const float*)d_in[11];

  char* ws = (char*)d_ws;
  size_t off = 0;
  auto alloc = [&](size_t bytes) -> char* {
    char* p = ws + off;
    off += (bytes + 255) & ~(size_t)255;
    return p;
  };
  // Combined mega weight: rows 0-2047 = W_ig, 2048-3103 = composed dt/B/C,
  // 3104-3199 = garbage pad (outputs discarded).
  bf16*  wmega_b = (bf16*)alloc((size_t)3200 * DM * 2);       // 6.25 MB
  bf16*  wstack_b= (bf16*)alloc((size_t)1152 * DM * 2);       // 2.25 MB
  bf16*  wigT_b  = (bf16*)alloc((size_t)DM * DM * 2);         // 2 MB
  bf16*  wout_b  = (bf16*)alloc((size_t)DM * DM * 2);         // 2 MB
  bf16*  xnorm_b = (bf16*)alloc((size_t)MROWS * DM * 2);      // 16 MB
  u32*   dx_w    = (u32*)alloc((size_t)MROWS * DM * 4);       // 32 MB packed (dt,xi)
  bf16*  z_bb    = (bf16*)alloc((size_t)MROWS * DM * 2);      // 16 MB
  bf16*  ssm_b   = (bf16*)alloc((size_t)MROWS * DM * 2);      // 16 MB
  float* Bt      = (float*)alloc((size_t)MROWS * NS * 4);     // 0.5 MB
  float* Ct      = (float*)alloc((size_t)MROWS * NS * 4);     // 0.5 MB
  (void)ws_size; (void)in_sizes; (void)n_in; (void)out_size;

  float* out_main = (float*)d_out;
  float* out_h    = (float*)d_out + (size_t)MROWS * DM;

  // 1) weight casts
  cast_f2b<<<(2 * DM * DM / 4 + 255) / 256, 256, 0, stream>>>(W_ig, wmega_b, 2 * DM * DM / 4);
  cast_f2b<<<(DM * DM / 4 + 255) / 256, 256, 0, stream>>>(W_dt, wstack_b, DM * DM / 4);
  cast_f2b<<<(NS * DM / 4 + 255) / 256, 256, 0, stream>>>(W_B, wstack_b + (size_t)DM * DM, NS * DM / 4);
  cast_f2b<<<(NS * DM / 4 + 255) / 256, 256, 0, stream>>>(W_C, wstack_b + (size_t)(DM + NS) * DM, NS * DM / 4);
  cast_f2b<<<(DM * DM / 4 + 255) / 256, 256, 0, stream>>>(W_out, wout_b, DM * DM / 4);
  // 2) W_ig[:1024]^T (for weight composition)
  transpose_cast<<<dim3(16, 16), 256, 0, stream>>>(W_ig, wigT_b);

  // 3) layernorm -> bf16
  ln_kernel<<<MROWS, 256, 0, stream>>>(x, ln_g, ln_b, xnorm_b);

  // 4) compose: wmega[2048+e][k] = sum_d [Wdt;WB;WC][e][d] * W_ig[d][k]
  gemm_bf16<3, false><<<dim3(8, 9), 256, 0, stream>>>(wstack_b, wigT_b, DM,
      nullptr, wmega_b + (size_t)2048 * DM, nullptr, nullptr, nullptr, nullptr);

  // 5) mega GEMM (M=8192, N=3104(pad 3200), K=1024), XCD-swizzled 1D grid:
  //    writes packed dx, z, B_t, C_t
  gemm_bf16<0, true><<<1600, 256, 0, stream>>>(xnorm_b, wmega_b, DM,
      nullptr, z_bb, (u16*)dx_w, b_dt, Bt, Ct);

  // 6) selective scan + fused gate -> ssm_b, h_final
  scan_kernel<<<512, 256, 0, stream>>>(dx_w, z_bb, Bt, Ct, A_log, h_prev,
                                       Dvec, ssm_b, out_h);

  // 7) output GEMM (M=8192, N=1024, K=1024) + residual x, XCD-swizzled
  gemm_bf16<2, true><<<512, 256, 0, stream>>>(ssm_b, wout_b, DM,
      out_main, nullptr, nullptr, x, nullptr, nullptr);
}

// Round 5
// 375.910 us; speedup vs baseline: 1.0562x; 1.0562x over previous
//
#include <hip/hip_runtime.h>
#include <hip/hip_bf16.h>
#include <math.h>

// Problem constants (fixed by setup_inputs)
#define DM 1024          // d_model
#define NS 16            // d_state
#define BSZ 8
#define LSEQ 1024
#define MROWS (BSZ*LSEQ) // 8192 token rows
#define CH 32            // scan chunk (timesteps staged per LDS buffer)

typedef __bf16 bf16;
typedef bf16 bf16x8 __attribute__((ext_vector_type(8)));
typedef bf16 bf16x4 __attribute__((ext_vector_type(4)));
typedef float f32x4 __attribute__((ext_vector_type(4)));
typedef unsigned int u32;
typedef unsigned short u16;

__device__ __forceinline__ void async16(const void* g, void* l) {
  __builtin_amdgcn_global_load_lds((const __attribute__((address_space(1))) void*)g,
                                   (__attribute__((address_space(3))) void*)l,
                                   16, 0, 0);
}

// packed (dt, xi) word: dt bf16 in low 16, xi bf16 in high 16
__device__ __forceinline__ float bflo(u32 u) { return __builtin_bit_cast(float, (u32)(u << 16)); }
__device__ __forceinline__ float bfhi(u32 u) { return __builtin_bit_cast(float, (u32)(u & 0xffff0000u)); }

// DPP row_ror add chain: 16-lane row reduction on the VALU pipe (no LDS traffic)
template <int CTRL>
__device__ __forceinline__ float dpp_add(float v) {
  int x = __builtin_amdgcn_update_dpp(0, __builtin_bit_cast(int, v), CTRL, 0xf, 0xf, true);
  return v + __builtin_bit_cast(float, x);
}
__device__ __forceinline__ float row_reduce16(float p) {
  p = dpp_add<0x121>(p);
  p = dpp_add<0x122>(p);
  p = dpp_add<0x124>(p);
  p = dpp_add<0x128>(p);
  return p;
}

// ---------------------------------------------------------------------------
// f32 -> bf16 cast (weights)
// ---------------------------------------------------------------------------
__global__ void cast_f2b(const float* __restrict__ s, bf16* __restrict__ d, int n4) {
  int i = blockIdx.x * 256 + threadIdx.x;
  if (i < n4) {
    float4 v = ((const float4*)s)[i];
    bf16x4 o;
    o.x = (bf16)v.x; o.y = (bf16)v.y; o.z = (bf16)v.z; o.w = (bf16)v.w;
    *(bf16x4*)(d + 4 * (size_t)i) = o;
  }
}

// ---------------------------------------------------------------------------
// Transpose + cast: dst[k][d] = (bf16) src[d][k], 1024x1024. 64x64 LDS tiles.
// ---------------------------------------------------------------------------
__global__ void transpose_cast(const float* __restrict__ src, bf16* __restrict__ dst) {
  __shared__ float tile[64][65];
  const int bk = blockIdx.x * 64;
  const int bd = blockIdx.y * 64;
  const int t = threadIdx.x;
  const int c4 = t & 15;
  const int r0 = t >> 4;
#pragma unroll
  for (int p = 0; p < 4; ++p) {
    int r = r0 + p * 16;
    float4 v = *(const float4*)(src + (size_t)(bd + r) * 1024 + bk + c4 * 4);
    tile[r][c4 * 4 + 0] = v.x;
    tile[r][c4 * 4 + 1] = v.y;
    tile[r][c4 * 4 + 2] = v.z;
    tile[r][c4 * 4 + 3] = v.w;
  }
  __syncthreads();
#pragma unroll
  for (int p = 0; p < 4; ++p) {
    int r = r0 + p * 16;
    bf16x4 o;
    o.x = (bf16)tile[c4 * 4 + 0][r];
    o.y = (bf16)tile[c4 * 4 + 1][r];
    o.z = (bf16)tile[c4 * 4 + 2][r];
    o.w = (bf16)tile[c4 * 4 + 3][r];
    *(bf16x4*)(dst + (size_t)(bk + r) * 1024 + bd + c4 * 4) = o;
  }
}

// ---------------------------------------------------------------------------
// LayerNorm over d=1024, writes bf16 x_norm. One block (256 thr) per row.
// ---------------------------------------------------------------------------
__global__ void ln_kernel(const float* __restrict__ x, const float* __restrict__ g,
                          const float* __restrict__ b, bf16* __restrict__ out) {
  const size_t row = blockIdx.x;
  const int t = threadIdx.x;
  float4 v = ((const float4*)(x + row * DM))[t];
  float s = v.x + v.y + v.z + v.w;
  float s2 = v.x*v.x + v.y*v.y + v.z*v.z + v.w*v.w;
#pragma unroll
  for (int m = 1; m < 64; m <<= 1) { s += __shfl_xor(s, m, 64); s2 += __shfl_xor(s2, m, 64); }
  __shared__ float red[8];
  int wave = t >> 6, lane = t & 63;
  if (lane == 0) { red[wave] = s; red[4 + wave] = s2; }
  __syncthreads();
  s  = red[0] + red[1] + red[2] + red[3];
  s2 = red[4] + red[5] + red[6] + red[7];
  float mu  = s * (1.f / DM);
  float var = s2 * (1.f / DM) - mu * mu;
  float inv = rsqrtf(var + 1e-5f);
  float4 gg = ((const float4*)g)[t];
  float4 bb = ((const float4*)b)[t];
  bf16x4 o;
  o.x = (bf16)((v.x - mu) * inv * gg.x + bb.x);
  o.y = (bf16)((v.y - mu) * inv * gg.y + bb.y);
  o.z = (bf16)((v.z - mu) * inv * gg.z + bb.z);
  o.w = (bf16)((v.w - mu) * inv * gg.w + bb.w);
  *(bf16x4*)(out + row * DM + t * 4) = o;
}

// ---------------------------------------------------------------------------
// MFMA bf16 GEMM: C[M,N] = A[M,K] @ W[N,K]^T. 128x128 tile, BK=64 (two 32-wide
// sub-stages per barrier pair). LDS k-chunks XOR-swizzled by (row>>1)&3 so
// ds_read_b128 fragments hit all 32 banks 2-way (was 8-way conflict).
// SWZ grid: blk%8 = XCD -> 8-m-tile stripe per XCD (A-stripe L2-resident).
// EPI 0 (mega): region-uniform per 64-wide wave tile:
//   n<1024 -> xi bf16; <2048 -> z bf16; <3072 -> softplus dt bf16;
//   tile 24: j==0 -> B_t f32, j==1 -> C_t f32, rest discard.
// EPI 2: out = acc + residual[m*DM+n]
// EPI 3 (compose): out_b[m*1024+n] = bf16(acc)
// ---------------------------------------------------------------------------
template <int EPI, bool SWZ>
__global__ __launch_bounds__(256)
void gemm_bf16(const bf16* __restrict__ A, const bf16* __restrict__ W, int K,
               float* __restrict__ out_f, bf16* __restrict__ out_b,
               u16* __restrict__ out_u1, u16* __restrict__ out_u2,
               const float* __restrict__ aux,
               float* __restrict__ out_f3, float* __restrict__ out_f4) {
  __shared__ bf16 As[2][128 * 32];
  __shared__ bf16 Bs[2][128 * 32];
  int tx, ty;
  if (SWZ) {
    int g = blockIdx.x;           // total = 8 XCD * 8 mloc * ntx
    int xcd = g & 7, slot = g >> 3;
    tx = slot >> 3;               // n-tile (n-major sweep within XCD)
    ty = xcd * 8 + (slot & 7);    // m-tile within this XCD's stripe
  } else {
    tx = blockIdx.x; ty = blockIdx.y;
  }
  const int tid  = threadIdx.x;
  const int wave = tid >> 6, lane = tid & 63;
  const int lr = lane & 15, quad = lane >> 4;
  const size_t arow = (size_t)ty * 128;
  const size_t brow = (size_t)tx * 128;
  f32x4 acc[4][4] = {};

  // staging: lane = (srl, kg); global k-chunk XOR-swizzled so LDS position kg
  // (fixed by hardware lane*16 dst) holds chunk kg^s(row), s(row)=(row>>1)&3.
  const int srl  = lane >> 2;          // row-local 0..15
  const int kg   = lane & 3;           // k-group 0..3
  const int srow = wave * 32 + srl;
  const int skc  = (kg ^ ((srl >> 1) & 3)) * 8;   // swizzled global k-offset (elems)
  const bf16* ag = A + (arow + srow) * (size_t)K + skc;
  const bf16* wg = W + (brow + srow) * (size_t)K + skc;
  bf16* asl0 = &As[0][wave * 32 * 32];
  bf16* asl1 = &As[1][wave * 32 * 32];
  bf16* bsl0 = &Bs[0][wave * 32 * 32];
  bf16* bsl1 = &Bs[1][wave * 32 * 32];

  // reader swizzle: global chunk quad of row lr(+16i) lives at position quad^s
  const int rk = (quad ^ ((lr >> 1) & 3)) * 8;

  for (int k0 = 0; k0 < K; k0 += 64) {
    async16(ag + k0,                       asl0);
    async16(ag + (size_t)16 * K + k0,      asl0 + 16 * 32);
    async16(ag + k0 + 32,                  asl1);
    async16(ag + (size_t)16 * K + k0 + 32, asl1 + 16 * 32);
    async16(wg + k0,                       bsl0);
    async16(wg + (size_t)16 * K + k0,      bsl0 + 16 * 32);
    async16(wg + k0 + 32,                  bsl1);
    async16(wg + (size_t)16 * K + k0 + 32, bsl1 + 16 * 32);
    __syncthreads();
#pragma unroll
    for (int kh = 0; kh < 2; ++kh) {
      const bf16* ap = &As[kh][(((wave >> 1) * 64) + lr) * 32 + rk];
      const bf16* bp = &Bs[kh][(((wave & 1) * 64) + lr) * 32 + rk];
      bf16x8 af[4], bfr[4];
#pragma unroll
      for (int i = 0; i < 4; ++i) af[i] = *(const bf16x8*)(ap + i * 16 * 32);
#pragma unroll
      for (int j = 0; j < 4; ++j) bfr[j] = *(const bf16x8*)(bp + j * 16 * 32);
#pragma unroll
      for (int i = 0; i < 4; ++i)
#pragma unroll
        for (int j = 0; j < 4; ++j)
          acc[i][j] = __builtin_amdgcn_mfma_f32_16x16x32_bf16(af[i], bfr[j], acc[i][j], 0, 0, 0);
    }
    __syncthreads();
  }

  // Epilogue. D layout (verified m89/m91): col = lane&15, row = quad*4 + reg.
  const size_t mbase = arow + (wave >> 1) * 64;
  const size_t nbase = brow + (wave & 1) * 64;
  if (EPI == 0) {
    if (nbase < DM) {                       // xi region (uniform per wave-tile)
#pragma unroll
      for (int i = 0; i < 4; ++i)
#pragma unroll
        for (int j = 0; j < 4; ++j)
#pragma unroll
          for (int r = 0; r < 4; ++r) {
            size_t m = mbase + i * 16 + quad * 4 + r;
            size_t n = nbase + j * 16 + lr;
            out_u1[m * DM + n] = __builtin_bit_cast(u16, (bf16)acc[i][j][r]);
          }
    } else if (nbase < 2 * DM) {            // z region
#pragma unroll
      for (int i = 0; i < 4; ++i)
#pragma unroll
        for (int j = 0; j < 4; ++j)
#pragma unroll
          for (int r = 0; r < 4; ++r) {
            size_t m = mbase + i * 16 + quad * 4 + r;
            size_t n = nbase - DM + j * 16 + lr;
            out_b[m * DM + n] = (bf16)acc[i][j][r];
          }
    } else if (nbase < 3 * DM) {            // dt region (softplus)
#pragma unroll
      for (int i = 0; i < 4; ++i)
#pragma unroll
        for (int j = 0; j < 4; ++j)
#pragma unroll
          for (int r = 0; r < 4; ++r) {
            size_t m = mbase + i * 16 + quad * 4 + r;
            size_t n = nbase - 2 * DM + j * 16 + lr;
            float tt = acc[i][j][r] + aux[n];
            float sp = (tt > 20.f) ? tt : __logf(1.f + __expf(tt));
            out_u2[m * DM + n] = __builtin_bit_cast(u16, (bf16)sp);
          }
    } else if (nbase < 3 * DM + 2 * NS) {   // B/C region (j==0 -> B, j==1 -> C)
#pragma unroll
      for (int i = 0; i < 4; ++i)
#pragma unroll
        for (int r = 0; r < 4; ++r) {
          size_t m = mbase + i * 16 + quad * 4 + r;
          out_f3[m * NS + lr] = acc[i][0][r];
          out_f4[m * NS + lr] = acc[i][1][r];
        }
    } // else: garbage pad columns, discard
  } else {
#pragma unroll
    for (int i = 0; i < 4; ++i)
#pragma unroll
      for (int j = 0; j < 4; ++j)
#pragma unroll
        for (int r = 0; r < 4; ++r) {
          size_t m = mbase + i * 16 + quad * 4 + r;
          size_t n = nbase + j * 16 + lr;
          float v = acc[i][j][r];
          if (EPI == 2) {
            out_f[m * DM + n] = v + aux[m * DM + n];
          } else {
            out_b[m * (size_t)DM + n] = (bf16)v;
          }
        }
  }
}

// ---------------------------------------------------------------------------
// Selective scan + fused output gate. Block = (batch b, 16 d-channels);
// thread (dl,n) owns h[b, d0+dl, n]. (dt,xi) packed into one LDS u32/element,
// DPP reduction, double-buffered chunks; writes ssm_out = y*silu(z)+xi*D bf16.
// ---------------------------------------------------------------------------
__global__ __launch_bounds__(256)
void scan_kernel(const u16* __restrict__ dt_b, const u16* __restrict__ xi_b,
                 const bf16* __restrict__ z_b,
                 const float* __restrict__ B_t, const float* __restrict__ C_t,
                 const float* __restrict__ A_log, const float* __restrict__ h_prev,
                 const float* __restrict__ Dvec,
                 bf16* __restrict__ ssm_out, float* __restrict__ h_final) {
  const int blk = blockIdx.x;        // 512 blocks
  const int b = blk >> 6;
  const int d0 = (blk & 63) * 16;
  const int t = threadIdx.x;
  const int n = t & 15, dl = t >> 4;
  const int d = d0 + dl;
  const float Ac2 = -__expf(A_log[d * NS + n]) * 1.44269504f;  // fold log2e
  float h = h_prev[(size_t)b * DM * NS + (size_t)d * NS + n];

  __shared__ u32    dxs[2][CH][16];  // packed (dt lo, xi hi) per (l, dl)
  __shared__ float2 bcs[2][CH][16];  // (B, C) per (l, n)
  __shared__ float  ys[CH][16];

  const size_t base_row = (size_t)b * LSEQ;
  const int l_a = t >> 4,  c_a = t & 15;
  const int l_b = l_a + 16, c_b = c_a;
  const float Dva = Dvec[d0 + c_a];

  float za, zb;
  {
    size_t ga = (base_row + l_a) * DM + d0 + c_a;
    size_t gb = (base_row + l_b) * DM + d0 + c_b;
    dxs[0][l_a][c_a] = (u32)dt_b[ga] | ((u32)xi_b[ga] << 16);
    dxs[0][l_b][c_b] = (u32)dt_b[gb] | ((u32)xi_b[gb] << 16);
    za = (float)z_b[ga]; zb = (float)z_b[gb];
    size_t gB = base_row * NS;
    bcs[0][l_a][c_a] = make_float2(B_t[gB + t],       C_t[gB + t]);
    bcs[0][l_b][c_b] = make_float2(B_t[gB + t + 256], C_t[gB + t + 256]);
  }
  __syncthreads();

  for (int c = 0; c < LSEQ / CH; ++c) {
    const int cur = c & 1, nxt = cur ^ 1;
    u32 pdxa, pdxb; float2 pbca, pbcb; float pza, pzb;
    if (c + 1 < LSEQ / CH) {
      size_t l0 = (size_t)(c + 1) * CH;
      size_t ga = (base_row + l0 + l_a) * DM + d0 + c_a;
      size_t gb = (base_row + l0 + l_b) * DM + d0 + c_b;
      pdxa = (u32)dt_b[ga] | ((u32)xi_b[ga] << 16);
      pdxb = (u32)dt_b[gb] | ((u32)xi_b[gb] << 16);
      pza = (float)z_b[ga]; pzb = (float)z_b[gb];
      size_t gB = (base_row + l0) * NS;
      pbca = make_float2(B_t[gB + t],       C_t[gB + t]);
      pbcb = make_float2(B_t[gB + t + 256], C_t[gB + t + 256]);
    }
#pragma unroll
    for (int l = 0; l < CH; ++l) {
      u32 u = dxs[cur][l][dl];
      float dtv = bflo(u), xiv = bfhi(u);
      float2 bc = bcs[cur][l][n];
      float a = __builtin_amdgcn_exp2f(dtv * Ac2);
      h = fmaf(a, h, (dtv * xiv) * bc.x);
      float p = row_reduce16(h * bc.y);
      if (n == 0) ys[l][dl] = p;
    }
    __syncthreads();
    {
      size_t l0 = (size_t)c * CH;
      float xa = bfhi(dxs[cur][l_a][c_a]);
      float xb = bfhi(dxs[cur][l_b][c_b]);
      float sa = za / (1.f + __expf(-za));
      float sb = zb / (1.f + __expf(-zb));
      ssm_out[(base_row + l0 + l_a) * DM + d0 + c_a] = (bf16)(ys[l_a][c_a] * sa + xa * Dva);
      ssm_out[(base_row + l0 + l_b) * DM + d0 + c_b] = (bf16)(ys[l_b][c_b] * sb + xb * Dva);
    }
    if (c + 1 < LSEQ / CH) {
      dxs[nxt][l_a][c_a] = pdxa;
      dxs[nxt][l_b][c_b] = pdxb;
      bcs[nxt][l_a][c_a] = pbca;
      bcs[nxt][l_b][c_b] = pbcb;
      za = pza; zb = pzb;
    }
    __syncthreads();
  }
  h_final[(size_t)b * DM * NS + (size_t)d0 * NS + t] = h;
}

// ---------------------------------------------------------------------------
extern "C" void kernel_launch(void* const* d_in, const int* in_sizes, int n_in,
                              void* d_out, int out_size, void* d_ws, size_t ws_size,
                              hipStream_t stream) {
  const float* x      = (const float*)d_in[0];
  const float* h_prev = (const float*)d_in[1];
  const float* ln_g   = (const float*)d_in[2];
  const float* ln_b   = (const float*)d_in[3];
  const float* W_ig   = (const float*)d_in[4];
  const float* W_dt   = (const float*)d_in[5];
  const float* b_dt   = (const float*)d_in[6];
  const float* A_log  = (const float*)d_in[7];
  const float* W_B    = (const float*)d_in[8];
  const float* W_C    = (const float*)d_in[9];
  const float* Dvec   = (const float*)d_in[10];
  const float* W_out  = (const float*)d_in[11];

  char* ws = (char*)d_ws;
  size_t off = 0;
  auto alloc = [&](size_t bytes) -> char* {
    char* p = ws + off;
    off += (bytes + 255) & ~(size_t)255;
    return p;
  };
  // Combined mega weight: rows 0-2047 = W_ig, 2048-3103 = composed dt/B/C,
  // 3104-3199 = garbage pad (outputs discarded).
  bf16*  wmega_b = (bf16*)alloc((size_t)3200 * DM * 2);       // 6.25 MB
  bf16*  wstack_b= (bf16*)alloc((size_t)1152 * DM * 2);       // 2.25 MB
  bf16*  wigT_b  = (bf16*)alloc((size_t)DM * DM * 2);         // 2 MB
  bf16*  wout_b  = (bf16*)alloc((size_t)DM * DM * 2);         // 2 MB
  bf16*  xnorm_b = (bf16*)alloc((size_t)MROWS * DM * 2);      // 16 MB
  u16*   xi_w    = (u16*)alloc((size_t)MROWS * DM * 2);       // 16 MB bf16 xi
  u16*   dt_w    = (u16*)alloc((size_t)MROWS * DM * 2);       // 16 MB bf16 dt
  bf16*  z_bb    = (bf16*)alloc((size_t)MROWS * DM * 2);      // 16 MB
  bf16*  ssm_b   = (bf16*)alloc((size_t)MROWS * DM * 2);      // 16 MB
  float* Bt      = (float*)alloc((size_t)MROWS * NS * 4);     // 0.5 MB
  float* Ct      = (float*)alloc((size_t)MROWS * NS * 4);     // 0.5 MB
  (void)ws_size; (void)in_sizes; (void)n_in; (void)out_size;

  float* out_main = (float*)d_out;
  float* out_h    = (float*)d_out + (size_t)MROWS * DM;

  // 1) weight casts
  cast_f2b<<<(2 * DM * DM / 4 + 255) / 256, 256, 0, stream>>>(W_ig, wmega_b, 2 * DM * DM / 4);
  cast_f2b<<<(DM * DM / 4 + 255) / 256, 256, 0, stream>>>(W_dt, wstack_b, DM * DM / 4);
  cast_f2b<<<(NS * DM / 4 + 255) / 256, 256, 0, stream>>>(W_B, wstack_b + (size_t)DM * DM, NS * DM / 4);
  cast_f2b<<<(NS * DM / 4 + 255) / 256, 256, 0, stream>>>(W_C, wstack_b + (size_t)(DM + NS) * DM, NS * DM / 4);
  cast_f2b<<<(DM * DM / 4 + 255) / 256, 256, 0, stream>>>(W_out, wout_b, DM * DM / 4);
  // 2) W_ig[:1024]^T (for weight composition)
  transpose_cast<<<dim3(16, 16), 256, 0, stream>>>(W_ig, wigT_b);

  // 3) layernorm -> bf16
  ln_kernel<<<MROWS, 256, 0, stream>>>(x, ln_g, ln_b, xnorm_b);

  // 4) compose: wmega[2048+e][k] = sum_d [Wdt;WB;WC][e][d] * W_ig[d][k]
  gemm_bf16<3, false><<<dim3(8, 9), 256, 0, stream>>>(wstack_b, wigT_b, DM,
      nullptr, wmega_b + (size_t)2048 * DM, nullptr, nullptr, nullptr, nullptr, nullptr);

  // 5) mega GEMM (M=8192, N=3104(pad 3200), K=1024), XCD-swizzled 1D grid:
  //    writes xi, z, dt, B_t, C_t
  gemm_bf16<0, true><<<1600, 256, 0, stream>>>(xnorm_b, wmega_b, DM,
      nullptr, z_bb, xi_w, dt_w, b_dt, Bt, Ct);

  // 6) selective scan + fused gate -> ssm_b, h_final
  scan_kernel<<<512, 256, 0, stream>>>(dt_w, xi_w, z_bb, Bt, Ct, A_log, h_prev,
                                       Dvec, ssm_b, out_h);

  // 7) output GEMM (M=8192, N=1024, K=1024) + residual x, XCD-swizzled
  gemm_bf16<2, true><<<512, 256, 0, stream>>>(ssm_b, wout_b, DM,
      out_main, nullptr, nullptr, nullptr, x, nullptr, nullptr);
}

// Round 6
// 344.991 us; speedup vs baseline: 1.1509x; 1.0896x over previous
//
#include <hip/hip_runtime.h>
#include <hip/hip_bf16.h>
#include <math.h>

// Problem constants (fixed by setup_inputs)
#define DM 1024          // d_model
#define NS 16            // d_state
#define BSZ 8
#define LSEQ 1024
#define MROWS (BSZ*LSEQ) // 8192 token rows
#define CH 32            // scan chunk (timesteps staged per LDS buffer)
#define ROWP 36          // padded LDS row length (words) for time-major buffers

typedef __bf16 bf16;
typedef bf16 bf16x8 __attribute__((ext_vector_type(8)));
typedef bf16 bf16x4 __attribute__((ext_vector_type(4)));
typedef float f32x4 __attribute__((ext_vector_type(4)));
typedef unsigned int u32;
typedef unsigned short u16;
typedef u32 u32x4 __attribute__((ext_vector_type(4)));

__device__ __forceinline__ void async16(const void* g, void* l) {
  __builtin_amdgcn_global_load_lds((const __attribute__((address_space(1))) void*)g,
                                   (__attribute__((address_space(3))) void*)l,
                                   16, 0, 0);
}

// packed (dt, xi) word: dt bf16 in low 16, xi bf16 in high 16
__device__ __forceinline__ float bflo(u32 u) { return __builtin_bit_cast(float, (u32)(u << 16)); }
__device__ __forceinline__ float bfhi(u32 u) { return __builtin_bit_cast(float, (u32)(u & 0xffff0000u)); }

// ---------------------------------------------------------------------------
// f32 -> bf16 cast (weights)
// ---------------------------------------------------------------------------
__global__ void cast_f2b(const float* __restrict__ s, bf16* __restrict__ d, int n4) {
  int i = blockIdx.x * 256 + threadIdx.x;
  if (i < n4) {
    float4 v = ((const float4*)s)[i];
    bf16x4 o;
    o.x = (bf16)v.x; o.y = (bf16)v.y; o.z = (bf16)v.z; o.w = (bf16)v.w;
    *(bf16x4*)(d + 4 * (size_t)i) = o;
  }
}

// ---------------------------------------------------------------------------
// Transpose + cast: dst[k][d] = (bf16) src[d][k], 1024x1024. 64x64 LDS tiles.
// ---------------------------------------------------------------------------
__global__ void transpose_cast(const float* __restrict__ src, bf16* __restrict__ dst) {
  __shared__ float tile[64][65];
  const int bk = blockIdx.x * 64;
  const int bd = blockIdx.y * 64;
  const int t = threadIdx.x;
  const int c4 = t & 15;
  const int r0 = t >> 4;
#pragma unroll
  for (int p = 0; p < 4; ++p) {
    int r = r0 + p * 16;
    float4 v = *(const float4*)(src + (size_t)(bd + r) * 1024 + bk + c4 * 4);
    tile[r][c4 * 4 + 0] = v.x;
    tile[r][c4 * 4 + 1] = v.y;
    tile[r][c4 * 4 + 2] = v.z;
    tile[r][c4 * 4 + 3] = v.w;
  }
  __syncthreads();
#pragma unroll
  for (int p = 0; p < 4; ++p) {
    int r = r0 + p * 16;
    bf16x4 o;
    o.x = (bf16)tile[c4 * 4 + 0][r];
    o.y = (bf16)tile[c4 * 4 + 1][r];
    o.z = (bf16)tile[c4 * 4 + 2][r];
    o.w = (bf16)tile[c4 * 4 + 3][r];
    *(bf16x4*)(dst + (size_t)(bk + r) * 1024 + bd + c4 * 4) = o;
  }
}

// ---------------------------------------------------------------------------
// LayerNorm over d=1024, writes bf16 x_norm. One block (256 thr) per row.
// ---------------------------------------------------------------------------
__global__ void ln_kernel(const float* __restrict__ x, const float* __restrict__ g,
                          const float* __restrict__ b, bf16* __restrict__ out) {
  const size_t row = blockIdx.x;
  const int t = threadIdx.x;
  float4 v = ((const float4*)(x + row * DM))[t];
  float s = v.x + v.y + v.z + v.w;
  float s2 = v.x*v.x + v.y*v.y + v.z*v.z + v.w*v.w;
#pragma unroll
  for (int m = 1; m < 64; m <<= 1) { s += __shfl_xor(s, m, 64); s2 += __shfl_xor(s2, m, 64); }
  __shared__ float red[8];
  int wave = t >> 6, lane = t & 63;
  if (lane == 0) { red[wave] = s; red[4 + wave] = s2; }
  __syncthreads();
  s  = red[0] + red[1] + red[2] + red[3];
  s2 = red[4] + red[5] + red[6] + red[7];
  float mu  = s * (1.f / DM);
  float var = s2 * (1.f / DM) - mu * mu;
  float inv = rsqrtf(var + 1e-5f);
  float4 gg = ((const float4*)g)[t];
  float4 bb = ((const float4*)b)[t];
  bf16x4 o;
  o.x = (bf16)((v.x - mu) * inv * gg.x + bb.x);
  o.y = (bf16)((v.y - mu) * inv * gg.y + bb.y);
  o.z = (bf16)((v.z - mu) * inv * gg.z + bb.z);
  o.w = (bf16)((v.w - mu) * inv * gg.w + bb.w);
  *(bf16x4*)(out + row * DM + t * 4) = o;
}

// ---------------------------------------------------------------------------
// MFMA bf16 GEMM: C[M,N] = A[M,K] @ W[N,K]^T. 128x128 tile, BK=64 (two 32-wide
// sub-stages per barrier pair). LDS k-chunks XOR-swizzled by (row>>1)&3 so
// ds_read_b128 fragments hit all 32 banks 2-way (was 8-way conflict).
// SWZ grid: blk%8 = XCD -> 8-m-tile stripe per XCD (A-stripe L2-resident).
// ---------------------------------------------------------------------------
template <int EPI, bool SWZ>
__global__ __launch_bounds__(256)
void gemm_bf16(const bf16* __restrict__ A, const bf16* __restrict__ W, int K,
               float* __restrict__ out_f, bf16* __restrict__ out_b,
               u16* __restrict__ out_u1, u16* __restrict__ out_u2,
               const float* __restrict__ aux,
               float* __restrict__ out_f3, float* __restrict__ out_f4) {
  __shared__ bf16 As[2][128 * 32];
  __shared__ bf16 Bs[2][128 * 32];
  int tx, ty;
  if (SWZ) {
    int g = blockIdx.x;           // total = 8 XCD * 8 mloc * ntx
    int xcd = g & 7, slot = g >> 3;
    tx = slot >> 3;               // n-tile (n-major sweep within XCD)
    ty = xcd * 8 + (slot & 7);    // m-tile within this XCD's stripe
  } else {
    tx = blockIdx.x; ty = blockIdx.y;
  }
  const int tid  = threadIdx.x;
  const int wave = tid >> 6, lane = tid & 63;
  const int lr = lane & 15, quad = lane >> 4;
  const size_t arow = (size_t)ty * 128;
  const size_t brow = (size_t)tx * 128;
  f32x4 acc[4][4] = {};

  const int srl  = lane >> 2;          // row-local 0..15
  const int kg   = lane & 3;           // k-group 0..3
  const int srow = wave * 32 + srl;
  const int skc  = (kg ^ ((srl >> 1) & 3)) * 8;   // swizzled global k-offset
  const bf16* ag = A + (arow + srow) * (size_t)K + skc;
  const bf16* wg = W + (brow + srow) * (size_t)K + skc;
  bf16* asl0 = &As[0][wave * 32 * 32];
  bf16* asl1 = &As[1][wave * 32 * 32];
  bf16* bsl0 = &Bs[0][wave * 32 * 32];
  bf16* bsl1 = &Bs[1][wave * 32 * 32];

  const int rk = (quad ^ ((lr >> 1) & 3)) * 8;

  for (int k0 = 0; k0 < K; k0 += 64) {
    async16(ag + k0,                       asl0);
    async16(ag + (size_t)16 * K + k0,      asl0 + 16 * 32);
    async16(ag + k0 + 32,                  asl1);
    async16(ag + (size_t)16 * K + k0 + 32, asl1 + 16 * 32);
    async16(wg + k0,                       bsl0);
    async16(wg + (size_t)16 * K + k0,      bsl0 + 16 * 32);
    async16(wg + k0 + 32,                  bsl1);
    async16(wg + (size_t)16 * K + k0 + 32, bsl1 + 16 * 32);
    __syncthreads();
#pragma unroll
    for (int kh = 0; kh < 2; ++kh) {
      const bf16* ap = &As[kh][(((wave >> 1) * 64) + lr) * 32 + rk];
      const bf16* bp = &Bs[kh][(((wave & 1) * 64) + lr) * 32 + rk];
      bf16x8 af[4], bfr[4];
#pragma unroll
      for (int i = 0; i < 4; ++i) af[i] = *(const bf16x8*)(ap + i * 16 * 32);
#pragma unroll
      for (int j = 0; j < 4; ++j) bfr[j] = *(const bf16x8*)(bp + j * 16 * 32);
#pragma unroll
      for (int i = 0; i < 4; ++i)
#pragma unroll
        for (int j = 0; j < 4; ++j)
          acc[i][j] = __builtin_amdgcn_mfma_f32_16x16x32_bf16(af[i], bfr[j], acc[i][j], 0, 0, 0);
    }
    __syncthreads();
  }

  // Epilogue. D layout (verified m89/m91): col = lane&15, row = quad*4 + reg.
  const size_t mbase = arow + (wave >> 1) * 64;
  const size_t nbase = brow + (wave & 1) * 64;
  if (EPI == 0) {
    if (nbase < DM) {                       // xi region
#pragma unroll
      for (int i = 0; i < 4; ++i)
#pragma unroll
        for (int j = 0; j < 4; ++j)
#pragma unroll
          for (int r = 0; r < 4; ++r) {
            size_t m = mbase + i * 16 + quad * 4 + r;
            size_t n = nbase + j * 16 + lr;
            out_u1[m * DM + n] = __builtin_bit_cast(u16, (bf16)acc[i][j][r]);
          }
    } else if (nbase < 2 * DM) {            // z region
#pragma unroll
      for (int i = 0; i < 4; ++i)
#pragma unroll
        for (int j = 0; j < 4; ++j)
#pragma unroll
          for (int r = 0; r < 4; ++r) {
            size_t m = mbase + i * 16 + quad * 4 + r;
            size_t n = nbase - DM + j * 16 + lr;
            out_b[m * DM + n] = (bf16)acc[i][j][r];
          }
    } else if (nbase < 3 * DM) {            // dt region (softplus)
#pragma unroll
      for (int i = 0; i < 4; ++i)
#pragma unroll
        for (int j = 0; j < 4; ++j)
#pragma unroll
          for (int r = 0; r < 4; ++r) {
            size_t m = mbase + i * 16 + quad * 4 + r;
            size_t n = nbase - 2 * DM + j * 16 + lr;
            float tt = acc[i][j][r] + aux[n];
            float sp = (tt > 20.f) ? tt : __logf(1.f + __expf(tt));
            out_u2[m * DM + n] = __builtin_bit_cast(u16, (bf16)sp);
          }
    } else if (nbase < 3 * DM + 2 * NS) {   // B/C region (j==0 -> B, j==1 -> C)
#pragma unroll
      for (int i = 0; i < 4; ++i)
#pragma unroll
        for (int r = 0; r < 4; ++r) {
          size_t m = mbase + i * 16 + quad * 4 + r;
          out_f3[m * NS + lr] = acc[i][0][r];
          out_f4[m * NS + lr] = acc[i][1][r];
        }
    } // else: garbage pad columns, discard
  } else {
#pragma unroll
    for (int i = 0; i < 4; ++i)
#pragma unroll
      for (int j = 0; j < 4; ++j)
#pragma unroll
        for (int r = 0; r < 4; ++r) {
          size_t m = mbase + i * 16 + quad * 4 + r;
          size_t n = nbase + j * 16 + lr;
          float v = acc[i][j][r];
          if (EPI == 2) {
            out_f[m * DM + n] = v + aux[m * DM + n];
          } else {
            out_b[m * (size_t)DM + n] = (bf16)v;
          }
        }
  }
}

// ---------------------------------------------------------------------------
// Selective scan + fused gate, v3. Block = (batch b, 16 d-channels); thread
// (dl,n) owns h[b, d0+dl, n]. Time-major padded LDS rows: inner loop reads 4
// timesteps per ds_read_b128 (forced batching, no per-step LDS latency).
// No DPP in the hot loop: lanes write h*C to ys_p; a per-chunk phase-2 sums
// over n, applies silu-gate + D-term, stores ssm_out bf16.
// ---------------------------------------------------------------------------
__global__ __launch_bounds__(256)
void scan_kernel(const u16* __restrict__ dt_b, const u16* __restrict__ xi_b,
                 const bf16* __restrict__ z_b,
                 const float* __restrict__ B_t, const float* __restrict__ C_t,
                 const float* __restrict__ A_log, const float* __restrict__ h_prev,
                 const float* __restrict__ Dvec,
                 bf16* __restrict__ ssm_out, float* __restrict__ h_final) {
  const int blk = blockIdx.x;        // 512 blocks
  const int b = blk >> 6;
  const int d0 = (blk & 63) * 16;
  const int t = threadIdx.x;
  const int n = t & 15, dl = t >> 4;     // compute role: channel dl, state n
  const int d = d0 + dl;
  const float Ac2 = -__expf(A_log[d * NS + n]) * 1.44269504f;  // fold log2e
  float h = h_prev[(size_t)b * DM * NS + (size_t)d * NS + n];

  // time-major LDS, rows padded to ROWP=36 words (b128-aligned, 2-way banks)
  __shared__ u32   dxs[2][16][ROWP];   // packed (dt lo, xi hi): [chan][l]
  __shared__ float Bsh[2][16][ROWP];   // [n][l]
  __shared__ float Csh[2][16][ROWP];   // [n][l]
  __shared__ float ys_p[CH][16][17];   // per-lane h*C partials: [l][chan][n]

  const size_t base_row = (size_t)b * LSEQ;
  // staging/output role: channel c_a, rows l_a and l_a+16
  const int l_a = t >> 4, c_a = t & 15;
  const float Dva = Dvec[d0 + c_a];

  // --- stage chunk 0 ---
  {
    size_t ga = (base_row + l_a) * DM + d0 + c_a;
    size_t gb = (base_row + l_a + 16) * DM + d0 + c_a;
    dxs[0][c_a][l_a]      = (u32)dt_b[ga] | ((u32)xi_b[ga] << 16);
    dxs[0][c_a][l_a + 16] = (u32)dt_b[gb] | ((u32)xi_b[gb] << 16);
    size_t gB = base_row * NS;
    Bsh[0][c_a][l_a]      = B_t[gB + t];
    Csh[0][c_a][l_a]      = C_t[gB + t];
    Bsh[0][c_a][l_a + 16] = B_t[gB + t + 256];
    Csh[0][c_a][l_a + 16] = C_t[gB + t + 256];
  }
  float za = (float)z_b[(base_row + l_a) * DM + d0 + c_a];
  float zb = (float)z_b[(base_row + l_a + 16) * DM + d0 + c_a];
  __syncthreads();

  for (int c = 0; c < LSEQ / CH; ++c) {
    const int cur = c & 1, nxt = cur ^ 1;
    // prefetch next chunk into registers (overlaps compute below)
    u32 pdxa, pdxb; float pBa, pBb, pCa, pCb, pza, pzb;
    if (c + 1 < LSEQ / CH) {
      size_t l0 = (size_t)(c + 1) * CH;
      size_t ga = (base_row + l0 + l_a) * DM + d0 + c_a;
      size_t gb = (base_row + l0 + l_a + 16) * DM + d0 + c_a;
      pdxa = (u32)dt_b[ga] | ((u32)xi_b[ga] << 16);
      pdxb = (u32)dt_b[gb] | ((u32)xi_b[gb] << 16);
      pza = (float)z_b[ga]; pzb = (float)z_b[gb];
      size_t gB = (base_row + l0) * NS;
      pBa = B_t[gB + t];       pCa = C_t[gB + t];
      pBb = B_t[gB + t + 256]; pCb = C_t[gB + t + 256];
    }
    // hot loop: 4 steps per LDS read batch; serial chain = fma only
#pragma unroll
    for (int l4 = 0; l4 < CH; l4 += 4) {
      u32x4 dx4 = *(const u32x4*)&dxs[cur][dl][l4];   // broadcast over n-lanes
      f32x4 b4  = *(const f32x4*)&Bsh[cur][n][l4];
      f32x4 c4  = *(const f32x4*)&Csh[cur][n][l4];
#pragma unroll
      for (int i = 0; i < 4; ++i) {
        float dtv = bflo(dx4[i]), xiv = bfhi(dx4[i]);
        float a = __builtin_amdgcn_exp2f(dtv * Ac2);
        h = fmaf(a, h, (dtv * xiv) * b4[i]);
        ys_p[l4 + i][dl][n] = h * c4[i];
      }
    }
    __syncthreads();
    // phase 2: sum over n, gate, store (thread t -> rows l_a, l_a+16, chan c_a)
    {
      float s1 = 0.f, s2 = 0.f;
#pragma unroll
      for (int k = 0; k < 16; ++k) {
        s1 += ys_p[l_a][c_a][k];
        s2 += ys_p[l_a + 16][c_a][k];
      }
      float x1 = bfhi(dxs[cur][c_a][l_a]);
      float x2 = bfhi(dxs[cur][c_a][l_a + 16]);
      float g1 = za / (1.f + __expf(-za));
      float g2 = zb / (1.f + __expf(-zb));
      size_t l0 = (size_t)c * CH;
      ssm_out[(base_row + l0 + l_a) * DM + d0 + c_a]      = (bf16)(s1 * g1 + x1 * Dva);
      ssm_out[(base_row + l0 + l_a + 16) * DM + d0 + c_a] = (bf16)(s2 * g2 + x2 * Dva);
    }
    if (c + 1 < LSEQ / CH) {
      dxs[nxt][c_a][l_a]      = pdxa;
      dxs[nxt][c_a][l_a + 16] = pdxb;
      Bsh[nxt][c_a][l_a]      = pBa;
      Csh[nxt][c_a][l_a]      = pCa;
      Bsh[nxt][c_a][l_a + 16] = pBb;
      Csh[nxt][c_a][l_a + 16] = pCb;
      za = pza; zb = pzb;
    }
    __syncthreads();
  }
  h_final[(size_t)b * DM * NS + (size_t)d0 * NS + t] = h;
}

// ---------------------------------------------------------------------------
extern "C" void kernel_launch(void* const* d_in, const int* in_sizes, int n_in,
                              void* d_out, int out_size, void* d_ws, size_t ws_size,
                              hipStream_t stream) {
  const float* x      = (const float*)d_in[0];
  const float* h_prev = (const float*)d_in[1];
  const float* ln_g   = (const float*)d_in[2];
  const float* ln_b   = (const float*)d_in[3];
  const float* W_ig   = (const float*)d_in[4];
  const float* W_dt   = (const float*)d_in[5];
  const float* b_dt   = (const float*)d_in[6];
  const float* A_log  = (const float*)d_in[7];
  const float* W_B    = (const float*)d_in[8];
  const float* W_C    = (const float*)d_in[9];
  const float* Dvec   = (const float*)d_in[10];
  const float* W_out  = (const float*)d_in[11];

  char* ws = (char*)d_ws;
  size_t off = 0;
  auto alloc = [&](size_t bytes) -> char* {
    char* p = ws + off;
    off += (bytes + 255) & ~(size_t)255;
    return p;
  };
  bf16*  wmega_b = (bf16*)alloc((size_t)3200 * DM * 2);       // 6.25 MB
  bf16*  wstack_b= (bf16*)alloc((size_t)1152 * DM * 2);       // 2.25 MB
  bf16*  wigT_b  = (bf16*)alloc((size_t)DM * DM * 2);         // 2 MB
  bf16*  wout_b  = (bf16*)alloc((size_t)DM * DM * 2);         // 2 MB
  bf16*  xnorm_b = (bf16*)alloc((size_t)MROWS * DM * 2);      // 16 MB
  u16*   xi_w    = (u16*)alloc((size_t)MROWS * DM * 2);       // 16 MB bf16 xi
  u16*   dt_w    = (u16*)alloc((size_t)MROWS * DM * 2);       // 16 MB bf16 dt
  bf16*  z_bb    = (bf16*)alloc((size_t)MROWS * DM * 2);      // 16 MB
  bf16*  ssm_b   = (bf16*)alloc((size_t)MROWS * DM * 2);      // 16 MB
  float* Bt      = (float*)alloc((size_t)MROWS * NS * 4);     // 0.5 MB
  float* Ct      = (float*)alloc((size_t)MROWS * NS * 4);     // 0.5 MB
  (void)ws_size; (void)in_sizes; (void)n_in; (void)out_size;

  float* out_main = (float*)d_out;
  float* out_h    = (float*)d_out + (size_t)MROWS * DM;

  // 1) weight casts
  cast_f2b<<<(2 * DM * DM / 4 + 255) / 256, 256, 0, stream>>>(W_ig, wmega_b, 2 * DM * DM / 4);
  cast_f2b<<<(DM * DM / 4 + 255) / 256, 256, 0, stream>>>(W_dt, wstack_b, DM * DM / 4);
  cast_f2b<<<(NS * DM / 4 + 255) / 256, 256, 0, stream>>>(W_B, wstack_b + (size_t)DM * DM, NS * DM / 4);
  cast_f2b<<<(NS * DM / 4 + 255) / 256, 256, 0, stream>>>(W_C, wstack_b + (size_t)(DM + NS) * DM, NS * DM / 4);
  cast_f2b<<<(DM * DM / 4 + 255) / 256, 256, 0, stream>>>(W_out, wout_b, DM * DM / 4);
  // 2) W_ig[:1024]^T (for weight composition)
  transpose_cast<<<dim3(16, 16), 256, 0, stream>>>(W_ig, wigT_b);

  // 3) layernorm -> bf16
  ln_kernel<<<MROWS, 256, 0, stream>>>(x, ln_g, ln_b, xnorm_b);

  // 4) compose: wmega[2048+e][k] = sum_d [Wdt;WB;WC][e][d] * W_ig[d][k]
  gemm_bf16<3, false><<<dim3(8, 9), 256, 0, stream>>>(wstack_b, wigT_b, DM,
      nullptr, wmega_b + (size_t)2048 * DM, nullptr, nullptr, nullptr, nullptr, nullptr);

  // 5) mega GEMM (M=8192, N=3104(pad 3200), K=1024), XCD-swizzled 1D grid:
  //    writes xi, z, dt, B_t, C_t
  gemm_bf16<0, true><<<1600, 256, 0, stream>>>(xnorm_b, wmega_b, DM,
      nullptr, z_bb, xi_w, dt_w, b_dt, Bt, Ct);

  // 6) selective scan + fused gate -> ssm_b, h_final
  scan_kernel<<<512, 256, 0, stream>>>(dt_w, xi_w, z_bb, Bt, Ct, A_log, h_prev,
                                       Dvec, ssm_b, out_h);

  // 7) output GEMM (M=8192, N=1024, K=1024) + residual x, XCD-swizzled
  gemm_bf16<2, true><<<512, 256, 0, stream>>>(ssm_b, wout_b, DM,
      out_main, nullptr, nullptr, nullptr, x, nullptr, nullptr);
}